// Round 1
// baseline (16.162 us; speedup 1.0000x reference)
//
#include <hip/hip_runtime.h>

#define NATOMS 128
#define QPT 2
#define BLOCK 256

#if defined(__has_builtin)
#if __has_builtin(__builtin_amdgcn_exp2f)
#define EXP2F(x) __builtin_amdgcn_exp2f(x)
#endif
#endif
#ifndef EXP2F
#define EXP2F(x) exp2f(x)
#endif

__global__ __launch_bounds__(BLOCK) void gnf_kernel(
    const float* __restrict__ coords,   // (128,3)
    const float* __restrict__ query,    // (M,3)
    float* __restrict__ out,            // (M,3)
    int M)
{
    __shared__ float4 sA[NATOMS];  // a.x, a.y, a.z, b   (log2e-folded)
    __shared__ float4 sC[NATOMS];  // c.x, c.y, c.z, 0

    const float LOG2E = 1.44269504088896340736f;
    const int tid = threadIdx.x;

    if (tid < NATOMS) {
        float cx = coords[tid * 3 + 0];
        float cy = coords[tid * 3 + 1];
        float cz = coords[tid * 3 + 2];
        sA[tid] = make_float4(cx * LOG2E, cy * LOG2E, cz * LOG2E,
                              -0.5f * (cx * cx + cy * cy + cz * cz) * LOG2E);
        sC[tid] = make_float4(cx, cy, cz, 0.0f);
    }
    __syncthreads();

    const int base = (blockIdx.x * BLOCK + tid) * QPT;
    if (base >= M) return;

    float qx[QPT], qy[QPT], qz[QPT], eq[QPT];
    float sw[QPT], sx[QPT], sy[QPT], sz[QPT];

#pragma unroll
    for (int k = 0; k < QPT; ++k) {
        const int m = base + k;
        const float x = query[m * 3 + 0];
        const float y = query[m * 3 + 1];
        const float z = query[m * 3 + 2];
        qx[k] = x; qy[k] = y; qz[k] = z;
        eq[k] = -0.5f * (x * x + y * y + z * z) * LOG2E;
        sw[k] = 0.0f; sx[k] = 0.0f; sy[k] = 0.0f; sz[k] = 0.0f;
    }

#pragma unroll 4
    for (int n = 0; n < NATOMS; ++n) {
        const float4 A = sA[n];
        const float4 C = sC[n];
#pragma unroll
        for (int k = 0; k < QPT; ++k) {
            // t = log2e * (c.q - 0.5|c|^2 - 0.5|q|^2)
            float t = fmaf(A.x, qx[k], fmaf(A.y, qy[k], fmaf(A.z, qz[k], A.w))) + eq[k];
            float w = EXP2F(t);
            sw[k] += w;
            sx[k] = fmaf(C.x, w, sx[k]);
            sy[k] = fmaf(C.y, w, sy[k]);
            sz[k] = fmaf(C.z, w, sz[k]);
        }
    }

#pragma unroll
    for (int k = 0; k < QPT; ++k) {
        const int m = base + k;
        // out = sum(c*w) - q * sum(w)
        out[m * 3 + 0] = fmaf(-qx[k], sw[k], sx[k]);
        out[m * 3 + 1] = fmaf(-qy[k], sw[k], sy[k]);
        out[m * 3 + 2] = fmaf(-qz[k], sw[k], sz[k]);
    }
}

extern "C" void kernel_launch(void* const* d_in, const int* in_sizes, int n_in,
                              void* d_out, int out_size, void* d_ws, size_t ws_size,
                              hipStream_t stream) {
    const float* coords = (const float*)d_in[0];
    const float* query  = (const float*)d_in[1];
    float* out = (float*)d_out;
    const int M = in_sizes[1] / 3;  // 262144
    const int threads = (M + QPT - 1) / QPT;
    const int grid = (threads + BLOCK - 1) / BLOCK;
    gnf_kernel<<<grid, BLOCK, 0, stream>>>(coords, query, out, M);
}